// Round 10
// baseline (98.434 us; speedup 1.0000x reference)
//
#include <hip/hip_runtime.h>

// Minimax Conv2D via L2-resident padded gather (no LDS, no barrier).
// out[b,o,h,w] = min_p( max_q( xp[b, conn-tap, h+kh, w+kw] - w1[o,3p+q] ) - w2[o,p] )
// Kernel 1: xp[16][64][66][66] replicate-padded copy of x into d_ws.
// Kernel 2: combined per-channel table: 9 gather deltas + 9 w1 + 3 w2 (24 dwords/ch).
// Kernel 3: lane = w (coalesced 256B gathers from L2); wave-uniform tap offsets via s_load;
//           grid.x = b so XCD = b%8 -> each XCD L2 caches 2 batch slabs (2.2 MB).

#define IN_C  64
#define OUT_C 128
#define BB    16
#define HH    64
#define WW    64
#define HP    66
#define WP    66
#define CSTR  (HP * WP)          // 4356 dwords per channel plane
#define BSTR  (IN_C * CSTR)      // 278784 dwords per batch slab
#define NPAD  (BB * BSTR)        // 4,460,544 elements
#define TABSTR 24                // dwords per output channel in combined table

__global__ __launch_bounds__(256)
void pad_x(const float* __restrict__ x, float* __restrict__ xp) {
    for (int i = blockIdx.x * 256 + threadIdx.x; i < NPAD; i += gridDim.x * 256) {
        int gw = i % WP;  int r  = i / WP;
        int gh = r % HP;  int r2 = r / HP;
        int c  = r2 % IN_C;
        int b  = r2 / IN_C;
        int sh = gh - 1; sh = sh < 0 ? 0 : (sh > HH - 1 ? HH - 1 : sh);
        int sw = gw - 1; sw = sw < 0 ? 0 : (sw > WW - 1 ? WW - 1 : sw);
        xp[i] = x[(((size_t)b * IN_C + c) * HH + sh) * WW + sw];
    }
}

__global__ __launch_bounds__(128)
void build_tab(const int* __restrict__ conn, const float* __restrict__ w1,
               const float* __restrict__ w2, int* __restrict__ tab) {
    const int o = threadIdx.x;          // 0..127, one thread per output channel
    int* tp = tab + o * TABSTR;
    float* fp = (float*)tp;
    #pragma unroll
    for (int t = 0; t < 9; ++t) {
        const int idx = conn[o * 9 + t];   // 0..575 = c*9 + kh*3 + kw
        const int c   = idx / 9;
        const int k   = idx - 9 * c;
        const int kh  = k / 3;
        const int kw  = k - 3 * kh;
        tp[t]     = c * CSTR + kh * WP + kw;   // dword delta within batch slab (h=0,w=0)
        fp[9 + t] = w1[o * 9 + t];
    }
    #pragma unroll
    for (int p = 0; p < 3; ++p) fp[18 + p] = w2[o * 3 + p];
}

__global__ __launch_bounds__(512, 8)     // 8 waves/EU min -> VGPR <= 64, 32 waves/CU
void mm_main(const float* __restrict__ xp, const int* __restrict__ tab,
             float* __restrict__ out) {
    const int tid  = threadIdx.x;
    const int lane = tid & 63;                                   // = w
    const int wid  = __builtin_amdgcn_readfirstlane(tid >> 6);   // 0..7
    const int b    = blockIdx.x;   // fastest grid dim -> XCD = b % 8
    const int h    = blockIdx.y;

    // scalar base: batch slab + output row; per-lane adds (tap delta + lane)
    const float* xb = xp + (size_t)b * BSTR + h * WP;

    for (int oo = 0; oo < 16; oo += 2) {
        const int o0 = wid * 16 + oo;          // wave-uniform
        const int* tp0 = tab + o0 * TABSTR;
        const int* tp1 = tp0 + TABSTR;
        const float* f0 = (const float*)tp0;
        const float* f1 = (const float*)tp1;

        // ---- issue all 18 coalesced gathers (wave-uniform delta + lane) ----
        float a0[9], a1[9];
        #pragma unroll
        for (int t = 0; t < 9; ++t) a0[t] = xb[tp0[t] + lane];
        #pragma unroll
        for (int t = 0; t < 9; ++t) a1[t] = xb[tp1[t] + lane];

        // ---- reduce ----
        float mi0, mi1;
        {
            float ma = a0[0] - f0[9 + 0];
            ma = fmaxf(ma, a0[1] - f0[9 + 1]);
            ma = fmaxf(ma, a0[2] - f0[9 + 2]);
            mi0 = ma - f0[18 + 0];
            ma = a0[3] - f0[9 + 3];
            ma = fmaxf(ma, a0[4] - f0[9 + 4]);
            ma = fmaxf(ma, a0[5] - f0[9 + 5]);
            mi0 = fminf(mi0, ma - f0[18 + 1]);
            ma = a0[6] - f0[9 + 6];
            ma = fmaxf(ma, a0[7] - f0[9 + 7]);
            ma = fmaxf(ma, a0[8] - f0[9 + 8]);
            mi0 = fminf(mi0, ma - f0[18 + 2]);
        }
        {
            float ma = a1[0] - f1[9 + 0];
            ma = fmaxf(ma, a1[1] - f1[9 + 1]);
            ma = fmaxf(ma, a1[2] - f1[9 + 2]);
            mi1 = ma - f1[18 + 0];
            ma = a1[3] - f1[9 + 3];
            ma = fmaxf(ma, a1[4] - f1[9 + 4]);
            ma = fmaxf(ma, a1[5] - f1[9 + 5]);
            mi1 = fminf(mi1, ma - f1[18 + 1]);
            ma = a1[6] - f1[9 + 6];
            ma = fmaxf(ma, a1[7] - f1[9 + 7]);
            ma = fmaxf(ma, a1[8] - f1[9 + 8]);
            mi1 = fminf(mi1, ma - f1[18 + 2]);
        }

        // ---- coalesced stores: 256 B per wave per channel ----
        out[(((size_t)b * OUT_C + o0) * HH + h) * WW + lane]     = mi0;
        out[(((size_t)b * OUT_C + o0 + 1) * HH + h) * WW + lane] = mi1;
    }
}

extern "C" void kernel_launch(void* const* d_in, const int* in_sizes, int n_in,
                              void* d_out, int out_size, void* d_ws, size_t ws_size,
                              hipStream_t stream) {
    const float* x    = (const float*)d_in[0];
    const float* w1   = (const float*)d_in[1];
    const float* w2   = (const float*)d_in[2];
    const int*   conn = (const int*)d_in[3];
    float*       out  = (float*)d_out;

    float* xp  = (float*)d_ws;                          // 17.8 MB padded x
    int*   tab = (int*)((char*)d_ws + (32u << 20));     // combined table at +32 MB

    pad_x<<<4096, 256, 0, stream>>>(x, xp);
    build_tab<<<1, 128, 0, stream>>>(conn, w1, w2, tab);

    dim3 grid(BB, HH);   // b fastest -> XCD = b % 8; 1024 blocks x 512 thr
    mm_main<<<grid, 512, 0, stream>>>(xp, tab, out);
}

// Round 11
// 97.860 us; speedup vs baseline: 1.0059x; 1.0059x over previous
//
#include <hip/hip_runtime.h>

// Minimax Conv2D via L2-resident padded gather (no LDS in hot kernel, no barrier).
// out[b,o,h,w] = min_p( max_q( xp[b, conn-tap, h+kh, w+kw] - w1[o,3p+q] ) - w2[o,p] )
// Kernel 1 (pad_and_tab): xp[16][64][66][66] replicate-padded copy of x, one wave per
//   padded row (coalesced read+write, no div/mod); block (0,0,0) also builds the
//   combined per-channel table (9 byte-deltas + 9 w1 + 3 w2 = 24 dwords/ch).
// Kernel 2 (mm_main): lane = w; every tap = wave-uniform s_load delta + lane ->
//   coalesced 256B L2 reads; grid.x = b so XCD = b%8 caches 2 batch slabs (2.2 MB).

#define IN_C  64
#define OUT_C 128
#define BB    16
#define HH    64
#define WW    64
#define HP    66
#define WP    66
#define CSTR  (HP * WP)          // 4356 dwords per channel plane
#define BSTR  (IN_C * CSTR)      // 278784 dwords per batch slab
#define TABSTR 24                // dwords per output channel in combined table

__global__ __launch_bounds__(256)
void pad_and_tab(const float* __restrict__ x, const int* __restrict__ conn,
                 const float* __restrict__ w1, const float* __restrict__ w2,
                 float* __restrict__ xp, int* __restrict__ tab) {
    const int tid = threadIdx.x;

    // ---- fold the table build into one block (saves a dispatch) ----
    if (blockIdx.x == 0 && blockIdx.y == 0 && blockIdx.z == 0 && tid < OUT_C) {
        const int o = tid;
        int*   tp = tab + o * TABSTR;
        float* fp = (float*)tp;
        #pragma unroll
        for (int t = 0; t < 9; ++t) {
            const int idx = conn[o * 9 + t];   // 0..575 = c*9 + kh*3 + kw
            const int c   = idx / 9;
            const int k   = idx - 9 * c;
            const int kh  = k / 3;
            const int kw  = k - 3 * kh;
            tp[t]     = c * CSTR + kh * WP + kw;   // dword delta within batch slab
            fp[9 + t] = w1[o * 9 + t];
        }
        #pragma unroll
        for (int p = 0; p < 3; ++p) fp[18 + p] = w2[o * 3 + p];
    }

    // ---- pad: one 64-lane wave row-copy per padded row ----
    const int rr   = tid >> 6;                 // row-in-block 0..3
    const int lane = tid & 63;                 // = src col
    const int gh   = blockIdx.x * 4 + rr;      // padded row 0..67 (skip >=66)
    const int c    = blockIdx.y;
    const int b    = blockIdx.z;
    if (gh < HP) {
        int sh = gh - 1; sh = sh < 0 ? 0 : (sh > HH - 1 ? HH - 1 : sh);
        const float v = x[(((size_t)b * IN_C + c) * HH + sh) * WW + lane];
        float* row = xp + (size_t)b * BSTR + c * CSTR + gh * WP;
        row[lane + 1] = v;                     // cols 1..64 (coalesced 256B)
        if (lane == 0)  row[0]  = v;           // left  replicate
        if (lane == 63) row[65] = v;           // right replicate
    }
}

__global__ __launch_bounds__(512, 8)     // 8 waves/EU min -> VGPR <= 64, 32 waves/CU
void mm_main(const float* __restrict__ xp, const int* __restrict__ tab,
             float* __restrict__ out) {
    const int tid  = threadIdx.x;
    const int lane = tid & 63;                                   // = w
    const int wid  = __builtin_amdgcn_readfirstlane(tid >> 6);   // 0..7
    const int b    = blockIdx.x;   // fastest grid dim -> XCD = b % 8
    const int h    = blockIdx.y;

    // scalar base: batch slab + output row; per-lane adds (tap delta + lane)
    const float* xb = xp + (size_t)b * BSTR + h * WP;

    for (int oo = 0; oo < 16; oo += 2) {
        const int o0 = wid * 16 + oo;          // wave-uniform
        const int* tp0 = tab + o0 * TABSTR;
        const int* tp1 = tp0 + TABSTR;
        const float* f0 = (const float*)tp0;
        const float* f1 = (const float*)tp1;

        // ---- issue all 18 coalesced gathers (wave-uniform delta + lane) ----
        float a0[9], a1[9];
        #pragma unroll
        for (int t = 0; t < 9; ++t) a0[t] = xb[tp0[t] + lane];
        #pragma unroll
        for (int t = 0; t < 9; ++t) a1[t] = xb[tp1[t] + lane];

        // ---- reduce ----
        float mi0, mi1;
        {
            float ma = a0[0] - f0[9 + 0];
            ma = fmaxf(ma, a0[1] - f0[9 + 1]);
            ma = fmaxf(ma, a0[2] - f0[9 + 2]);
            mi0 = ma - f0[18 + 0];
            ma = a0[3] - f0[9 + 3];
            ma = fmaxf(ma, a0[4] - f0[9 + 4]);
            ma = fmaxf(ma, a0[5] - f0[9 + 5]);
            mi0 = fminf(mi0, ma - f0[18 + 1]);
            ma = a0[6] - f0[9 + 6];
            ma = fmaxf(ma, a0[7] - f0[9 + 7]);
            ma = fmaxf(ma, a0[8] - f0[9 + 8]);
            mi0 = fminf(mi0, ma - f0[18 + 2]);
        }
        {
            float ma = a1[0] - f1[9 + 0];
            ma = fmaxf(ma, a1[1] - f1[9 + 1]);
            ma = fmaxf(ma, a1[2] - f1[9 + 2]);
            mi1 = ma - f1[18 + 0];
            ma = a1[3] - f1[9 + 3];
            ma = fmaxf(ma, a1[4] - f1[9 + 4]);
            ma = fmaxf(ma, a1[5] - f1[9 + 5]);
            mi1 = fminf(mi1, ma - f1[18 + 1]);
            ma = a1[6] - f1[9 + 6];
            ma = fmaxf(ma, a1[7] - f1[9 + 7]);
            ma = fmaxf(ma, a1[8] - f1[9 + 8]);
            mi1 = fminf(mi1, ma - f1[18 + 2]);
        }

        // ---- coalesced stores: 256 B per wave per channel ----
        out[(((size_t)b * OUT_C + o0) * HH + h) * WW + lane]     = mi0;
        out[(((size_t)b * OUT_C + o0 + 1) * HH + h) * WW + lane] = mi1;
    }
}

extern "C" void kernel_launch(void* const* d_in, const int* in_sizes, int n_in,
                              void* d_out, int out_size, void* d_ws, size_t ws_size,
                              hipStream_t stream) {
    const float* x    = (const float*)d_in[0];
    const float* w1   = (const float*)d_in[1];
    const float* w2   = (const float*)d_in[2];
    const int*   conn = (const int*)d_in[3];
    float*       out  = (float*)d_out;

    float* xp  = (float*)d_ws;                          // 17.8 MB padded x
    int*   tab = (int*)((char*)d_ws + (32u << 20));     // combined table at +32 MB

    dim3 pgrid((HP + 3) / 4, IN_C, BB);   // 17 x 64 x 16 wave-per-row copy
    pad_and_tab<<<pgrid, 256, 0, stream>>>(x, conn, w1, w2, xp, tab);

    dim3 grid(BB, HH);   // b fastest -> XCD = b % 8; 1024 blocks x 512 thr
    mm_main<<<grid, 512, 0, stream>>>(xp, tab, out);
}